// Round 3
// baseline (133.193 us; speedup 1.0000x reference)
//
#include <hip/hip_runtime.h>

#define B_TOTAL 16384
#define F_DIM 512
#define H_DIM 256
#define E_NUM 8
#define OUT_COLS 32
#define DA 8
#define TM 32                 // samples per block
#define HSTRIDE (H_DIM + 8)   // 264 halves: rows 16B-aligned, bank-stride 4
#define C_CAP 96              // per-expert block capacity (8*C_CAP >= max tiles: robust)
#define MLP_BLOCKS (E_NUM * C_CAP)  // 768
#define SETUP_BLOCKS 456      // 384 transpose(4 tiles ea) + 8 W3 + 64 bucket

typedef __attribute__((ext_vector_type(8))) _Float16 half8;
typedef __attribute__((ext_vector_type(4))) _Float16 half4;
typedef __attribute__((ext_vector_type(4))) float float4v;

// ---------------- merged setup: weight prep + bucket in one dispatch ----------------
// blocks 0..383: W1/W2 transpose, 4 32x32 tiles each; 384..391: W3 pack; 392..455: bucket
__global__ void k_setup(const float* __restrict__ W1, const float* __restrict__ W2,
                        const float* __restrict__ W3,
                        _Float16* __restrict__ W1t, _Float16* __restrict__ W2t,
                        _Float16* __restrict__ W3t,
                        const int* __restrict__ act, int* __restrict__ counts,
                        int* __restrict__ idxbuf) {
  int bid = blockIdx.x;
  if (bid >= 392) {
    // ---- bucket samples by expert (block-aggregated atomics) ----
    __shared__ int wcnt[4][E_NUM];
    __shared__ int wbase[4][E_NUM];
    int t = threadIdx.x;
    int lane = t & 63, wave = t >> 6;
    int b = (bid - 392) * 256 + t;
    int e = act[b] & 7;

    unsigned long long mymask = 0;
#pragma unroll
    for (int v = 0; v < E_NUM; ++v) {
      unsigned long long m = __ballot(e == v);
      if (lane == 0) wcnt[wave][v] = (int)__popcll(m);
      if (e == v) mymask = m;
    }
    int rank = (int)__popcll(mymask & ((1ull << lane) - 1ull));
    __syncthreads();
    if (t < E_NUM) {
      int c0 = wcnt[0][t], c1 = wcnt[1][t], c2 = wcnt[2][t], c3 = wcnt[3][t];
      int base = atomicAdd(&counts[t], c0 + c1 + c2 + c3);
      wbase[0][t] = base;
      wbase[1][t] = base + c0;
      wbase[2][t] = base + c0 + c1;
      wbase[3][t] = base + c0 + c1 + c2;
    }
    __syncthreads();
    idxbuf[e * B_TOTAL + wbase[wave][e] + rank] = b;
    return;
  }

  if (bid >= 384) {            // W3: (256,32) -> (16,256) with rows 8..15 = 0
    int e = bid - 384;
    int k = threadIdx.x;
#pragma unroll
    for (int o = 0; o < 16; ++o) {
      float v = (o < DA) ? W3[((size_t)e * H_DIM + k) * OUT_COLS + o] : 0.f;
      W3t[((size_t)e * 16 + o) * H_DIM + k] = (_Float16)v;
    }
    return;
  }

  // ---- weight transpose: 4 consecutive 32x32 tiles per block ----
  __shared__ float tile[32][33];
  int tx = threadIdx.x & 31, ty = threadIdx.x >> 5;  // 32x8
  for (int rep = 0; rep < 4; ++rep) {
    int tb = bid * 4 + rep;    // 0..1535
    const float* S; _Float16* D; int K, N, k0, n0;
    if (tb < 1024) {           // W1: (512,256) -> (256,512), 128 tiles/expert
      int e = tb >> 7, tt = tb & 127;
      K = F_DIM; N = H_DIM; k0 = (tt >> 3) * 32; n0 = (tt & 7) * 32;
      S = W1 + (size_t)e * F_DIM * H_DIM;
      D = W1t + (size_t)e * H_DIM * F_DIM;
    } else {                   // W2: (256,256) -> (256,256), 64 tiles/expert
      int r = tb - 1024;
      int e = r >> 6, tt = r & 63;
      K = H_DIM; N = H_DIM; k0 = (tt >> 3) * 32; n0 = (tt & 7) * 32;
      S = W2 + (size_t)e * H_DIM * H_DIM;
      D = W2t + (size_t)e * H_DIM * H_DIM;
    }
#pragma unroll
    for (int r = 0; r < 32; r += 8)
      tile[ty + r][tx] = S[(size_t)(k0 + ty + r) * N + (n0 + tx)];
    __syncthreads();
#pragma unroll
    for (int r = 0; r < 32; r += 8)
      D[(size_t)(n0 + ty + r) * K + (k0 + tx)] = (_Float16)tile[tx][ty + r];
    __syncthreads();           // WAR on tile before next rep
  }
}

// ---------------- fused gather + 3-layer expert MLP (XCD-pinned experts) -------------
// Block bid handles expert (bid&7), tile (bid>>3): expert e's blocks land on XCD e ->
// expert weights are L2-resident in one XCD. (e,tile) known at cycle 0 -> idxbuf and
// weight loads issue speculatively, in parallel with the counts read. Orphan blocks
// (li >= tiles(e)) cover leftover tiles of any over-full expert: provably covering
// since 8*C_CAP=768 >= total tiles (<=519).
__global__ __launch_bounds__(512, 8) void k_mlp(
    const float* __restrict__ X,
    const _Float16* __restrict__ W1t,
    const _Float16* __restrict__ W2t,
    const _Float16* __restrict__ W3t,
    const float* __restrict__ b1,
    const float* __restrict__ b2,
    const float* __restrict__ b3,
    const int* __restrict__ counts,
    const int* __restrict__ idxbuf,
    float* __restrict__ out)
{
  __shared__ _Float16 bufA[TM][HSTRIDE];  // X cols 0..255, later H2
  __shared__ _Float16 bufB[TM][HSTRIDE];  // X cols 256..511, later H1

  int t = threadIdx.x;
  int lane = t & 63;
  int wave = t >> 6;          // 0..7
  int quad = lane >> 4;
  int l16 = lane & 15;
  int hbase = wave * 32;      // 32 hidden rows per wave
  int kq = quad * 8;
  int s = t >> 4, sub = t & 15;

  int x = blockIdx.x & 7;
  int li = blockIdx.x >> 3;

  // --- speculative idxbuf load (primary mapping), issued at cycle 0 ---
  int raw = idxbuf[x * B_TOTAL + li * TM + s];

  // --- counts (uniform) + primary/orphan mapping ---
  int cnt_x = counts[x];
  int tt_x = (cnt_x + 31) >> 5;
  int e = x, tile = li, cnt = cnt_x;
  if (li >= tt_x) {
    // orphan remap (rare; handles skewed expert distributions)
    int ttj[E_NUM];
#pragma unroll
    for (int j = 0; j < E_NUM; ++j) ttj[j] = (counts[j] + 31) >> 5;
    int rank = 0;
#pragma unroll
    for (int j = 0; j < E_NUM; ++j) { int d = li - ttj[j]; rank += d > 0 ? d : 0; }
#pragma unroll
    for (int j = 0; j < E_NUM; ++j) if (j < x && li >= ttj[j]) ++rank;
    int fe = -1, ft = 0, accum = 0;
#pragma unroll
    for (int j = 0; j < E_NUM; ++j) {
      int lo = ttj[j] - C_CAP; lo = lo > 0 ? lo : 0;
      if (fe < 0 && rank < accum + lo) { fe = j; ft = C_CAP + (rank - accum); }
      accum += lo;
    }
    if (fe < 0) return;
    e = fe; tile = ft; cnt = counts[e];
    raw = idxbuf[e * B_TOTAL + tile * TM + s];
  }
  int tile0 = tile * TM;

  const float4v vzero = {0.f, 0.f, 0.f, 0.f};
  bool valid = (tile0 + s) < cnt;
  int xrow = raw & (B_TOTAL - 1);   // clamp: speculative entries may be garbage
  const float* src = X + (size_t)xrow * F_DIM;

  // --- X gather: chunk1 (cols 256..511) into regs, chunk0 -> bufA ---
  float4v c1reg[4];
#pragma unroll
  for (int i = 0; i < 4; ++i) {
    int c = sub * 4 + i * 64;
    c1reg[i] = *(const float4v*)(src + 256 + c);
  }
#pragma unroll
  for (int i = 0; i < 4; ++i) {
    int c = sub * 4 + i * 64;
    float4v v = *(const float4v*)(src + c);
    if (!valid) v = vzero;
    half4 h;
    h[0] = (_Float16)v.x; h[1] = (_Float16)v.y;
    h[2] = (_Float16)v.z; h[3] = (_Float16)v.w;
    *(half4*)&bufA[s][c] = h;
  }

  // --- layer-1 weight prefetch (depth-3 modulo pipeline, 2 m-tiles) ---
  const _Float16* wb = W1t + ((size_t)e * H_DIM + hbase + l16) * F_DIM + kq;
  half8 a_p[3][2];
#pragma unroll
  for (int p = 0; p < 3; ++p)
#pragma unroll
    for (int mt = 0; mt < 2; ++mt)
      a_p[p][mt] = *(const half8*)(wb + (size_t)mt * 16 * F_DIM + p * 32);

  __syncthreads();

  float4v acc[2][2];
#pragma unroll
  for (int mt = 0; mt < 2; ++mt)
#pragma unroll
    for (int st = 0; st < 2; ++st) acc[mt][st] = vzero;

  // ======== Layer 1a: kb 0..255 from bufA (chunk1 loads still in flight) ========
#pragma unroll
  for (int kb = 0; kb < 256; kb += 32) {
    int p = (kb >> 5) % 3;
    half8 a_cur[2];
#pragma unroll
    for (int mt = 0; mt < 2; ++mt) a_cur[mt] = a_p[p][mt];
#pragma unroll
    for (int mt = 0; mt < 2; ++mt)
      a_p[p][mt] = *(const half8*)(wb + (size_t)mt * 16 * F_DIM + kb + 96);
    half8 b_cur[2];
#pragma unroll
    for (int st = 0; st < 2; ++st)
      b_cur[st] = *(const half8*)&bufA[st * 16 + l16][kb + kq];
#pragma unroll
    for (int mt = 0; mt < 2; ++mt)
#pragma unroll
      for (int st = 0; st < 2; ++st)
        acc[mt][st] = __builtin_amdgcn_mfma_f32_16x16x32_f16(a_cur[mt], b_cur[st], acc[mt][st], 0, 0, 0);
  }

  // --- land chunk1 into bufB (loads have been hiding under layer 1a) ---
#pragma unroll
  for (int i = 0; i < 4; ++i) {
    int c = sub * 4 + i * 64;
    float4v v = c1reg[i];
    if (!valid) v = vzero;
    half4 h;
    h[0] = (_Float16)v.x; h[1] = (_Float16)v.y;
    h[2] = (_Float16)v.z; h[3] = (_Float16)v.w;
    *(half4*)&bufB[s][c] = h;
  }
  __syncthreads();

  // ======== Layer 1b: kb 256..511 from bufB ========
#pragma unroll
  for (int kb = 256; kb < F_DIM; kb += 32) {
    int p = (kb >> 5) % 3;
    half8 a_cur[2];
#pragma unroll
    for (int mt = 0; mt < 2; ++mt) a_cur[mt] = a_p[p][mt];
    if (kb + 96 < F_DIM) {
#pragma unroll
      for (int mt = 0; mt < 2; ++mt)
        a_p[p][mt] = *(const half8*)(wb + (size_t)mt * 16 * F_DIM + kb + 96);
    }
    half8 b_cur[2];
#pragma unroll
    for (int st = 0; st < 2; ++st)
      b_cur[st] = *(const half8*)&bufB[st * 16 + l16][kb - 256 + kq];
#pragma unroll
    for (int mt = 0; mt < 2; ++mt)
#pragma unroll
      for (int st = 0; st < 2; ++st)
        acc[mt][st] = __builtin_amdgcn_mfma_f32_16x16x32_f16(a_cur[mt], b_cur[st], acc[mt][st], 0, 0, 0);
  }

  // --- issue layer-2 weight prefetch before barrier (overlaps epilogue) ---
  const _Float16* wb2 = W2t + ((size_t)e * H_DIM + hbase + l16) * H_DIM + kq;
#pragma unroll
  for (int p = 0; p < 3; ++p)
#pragma unroll
    for (int mt = 0; mt < 2; ++mt)
      a_p[p][mt] = *(const half8*)(wb2 + (size_t)mt * 16 * H_DIM + p * 32);

  __syncthreads();  // all waves done reading bufB as X before H1 lands there

  // layer-1 epilogue: bias + relu -> bufB (= H1[sample][hidden])
#pragma unroll
  for (int mt = 0; mt < 2; ++mt) {
    int h0 = hbase + mt * 16 + quad * 4;
    float4v bb = *(const float4v*)&b1[e * H_DIM + h0];
#pragma unroll
    for (int st = 0; st < 2; ++st) {
      half4 hv;
#pragma unroll
      for (int r = 0; r < 4; ++r) {
        float v = acc[mt][st][r] + bb[r];
        hv[r] = (_Float16)(v > 0.f ? v : 0.f);
      }
      *(half4*)&bufB[st * 16 + l16][h0] = hv;
    }
  }
  __syncthreads();

  // ======== Layer 2: H2^T[h][s] = sum_k W2t[h][k] * H1[s][k] ========
#pragma unroll
  for (int mt = 0; mt < 2; ++mt)
#pragma unroll
    for (int st = 0; st < 2; ++st) acc[mt][st] = vzero;

#pragma unroll
  for (int kb = 0; kb < H_DIM; kb += 32) {
    int p = (kb >> 5) % 3;
    half8 a_cur[2];
#pragma unroll
    for (int mt = 0; mt < 2; ++mt) a_cur[mt] = a_p[p][mt];
    if (kb + 96 < H_DIM) {
#pragma unroll
      for (int mt = 0; mt < 2; ++mt)
        a_p[p][mt] = *(const half8*)(wb2 + (size_t)mt * 16 * H_DIM + kb + 96);
    }
    half8 b_cur[2];
#pragma unroll
    for (int st = 0; st < 2; ++st)
      b_cur[st] = *(const half8*)&bufB[st * 16 + l16][kb + kq];
#pragma unroll
    for (int mt = 0; mt < 2; ++mt)
#pragma unroll
      for (int st = 0; st < 2; ++st)
        acc[mt][st] = __builtin_amdgcn_mfma_f32_16x16x32_f16(a_cur[mt], b_cur[st], acc[mt][st], 0, 0, 0);
  }

  // layer-2 epilogue -> bufA (= H2; X chunk0 dead, nobody reads bufA during L2)
#pragma unroll
  for (int mt = 0; mt < 2; ++mt) {
    int h0 = hbase + mt * 16 + quad * 4;
    float4v bb = *(const float4v*)&b2[e * H_DIM + h0];
#pragma unroll
    for (int st = 0; st < 2; ++st) {
      half4 hv;
#pragma unroll
      for (int r = 0; r < 4; ++r) {
        float v = acc[mt][st][r] + bb[r];
        hv[r] = (_Float16)(v > 0.f ? v : 0.f);
      }
      *(half4*)&bufA[st * 16 + l16][h0] = hv;
    }
  }

  // --- waves 0,1: prefetch W3 before the barrier ---
  half8 af[8];
  const _Float16* wb3 = W3t + ((size_t)e * 16 + l16) * H_DIM + kq;
  if (wave < 2) {
#pragma unroll
    for (int i = 0; i < 8; ++i) af[i] = *(const half8*)(wb3 + i * 32);
  }
  __syncthreads();

  // ======== Layer 3: waves 0,1 each compute one 16-sample out tile ========
  if (wave < 2) {
    float4v acc3 = vzero;
#pragma unroll
    for (int i = 0; i < 8; ++i) {
      half8 bfrag = *(const half8*)&bufA[wave * 16 + l16][i * 32 + kq];
      acc3 = __builtin_amdgcn_mfma_f32_16x16x32_f16(af[i], bfrag, acc3, 0, 0, 0);
    }
    int si = tile0 + wave * 16 + l16;
    if (quad < 2 && si < cnt) {
      int row = idxbuf[e * B_TOTAL + si];
      float4v bb = *(const float4v*)&b3[e * OUT_COLS + quad * 4];
      float4v y;
#pragma unroll
      for (int r = 0; r < 4; ++r) y[r] = acc3[r] + bb[r];
      *(float4v*)&out[(size_t)row * DA + quad * 4] = y;
    }
  }
}

extern "C" void kernel_launch(void* const* d_in, const int* in_sizes, int n_in,
                              void* d_out, int out_size, void* d_ws, size_t ws_size,
                              hipStream_t stream) {
  const float* features = (const float*)d_in[0];
  const float* W1 = (const float*)d_in[1];
  const float* b1 = (const float*)d_in[2];
  const float* W2 = (const float*)d_in[3];
  const float* b2 = (const float*)d_in[4];
  const float* W3 = (const float*)d_in[5];
  const float* b3 = (const float*)d_in[6];
  const int* act = (const int*)d_in[7];
  float* out = (float*)d_out;

  char* ws = (char*)d_ws;
  int* counts = (int*)ws;                                      // 256 B
  int* idxbuf = (int*)(ws + 256);                              // 512 KiB
  _Float16* W1t = (_Float16*)(ws + 256 + 524288);              // 2 MiB
  _Float16* W2t = (_Float16*)(ws + 256 + 524288 + 2097152);    // 1 MiB
  _Float16* W3t = (_Float16*)(ws + 256 + 524288 + 2097152 + 1048576);  // 64 KiB

  hipMemsetAsync(counts, 0, 256, stream);
  k_setup<<<SETUP_BLOCKS, 256, 0, stream>>>(W1, W2, W3, W1t, W2t, W3t,
                                            act, counts, idxbuf);
  k_mlp<<<MLP_BLOCKS, 512, 0, stream>>>(features, W1t, W2t, W3t,
                                        b1, b2, b3, counts, idxbuf, out);
}

// Round 4
// 126.516 us; speedup vs baseline: 1.0528x; 1.0528x over previous
//
#include <hip/hip_runtime.h>

#define B_TOTAL 16384
#define F_DIM 512
#define H_DIM 256
#define E_NUM 8
#define OUT_COLS 32
#define DA 8
#define TM 32                 // samples per block
#define HSTRIDE (H_DIM + 8)   // 264 halves: rows 16B-aligned; wave64 b128 reads conflict-free
#define MLP_BLOCKS ((B_TOTAL + E_NUM * (TM - 1) + TM - 1) / TM)  // 520
#define SETUP_BLOCKS 456      // 384 transpose(4 tiles ea) + 8 W3 + 64 bucket

typedef __attribute__((ext_vector_type(8))) _Float16 half8;
typedef __attribute__((ext_vector_type(4))) _Float16 half4;
typedef __attribute__((ext_vector_type(4))) float float4v;

// ---------------- merged setup: weight prep + bucket in one dispatch ----------------
// blocks 0..383: W1/W2 transpose, 4 32x32 tiles each; 384..391: W3 pack; 392..455: bucket
__global__ void k_setup(const float* __restrict__ W1, const float* __restrict__ W2,
                        const float* __restrict__ W3,
                        _Float16* __restrict__ W1t, _Float16* __restrict__ W2t,
                        _Float16* __restrict__ W3t,
                        const int* __restrict__ act, int* __restrict__ counts,
                        int* __restrict__ idxbuf) {
  int bid = blockIdx.x;
  if (bid >= 392) {
    // ---- bucket samples by expert (block-aggregated atomics) ----
    __shared__ int wcnt[4][E_NUM];
    __shared__ int wbase[4][E_NUM];
    int t = threadIdx.x;
    int lane = t & 63, wave = t >> 6;
    int b = (bid - 392) * 256 + t;
    int e = act[b] & 7;

    unsigned long long mymask = 0;
#pragma unroll
    for (int v = 0; v < E_NUM; ++v) {
      unsigned long long m = __ballot(e == v);
      if (lane == 0) wcnt[wave][v] = (int)__popcll(m);
      if (e == v) mymask = m;
    }
    int rank = (int)__popcll(mymask & ((1ull << lane) - 1ull));
    __syncthreads();
    if (t < E_NUM) {
      int c0 = wcnt[0][t], c1 = wcnt[1][t], c2 = wcnt[2][t], c3 = wcnt[3][t];
      int base = atomicAdd(&counts[t], c0 + c1 + c2 + c3);
      wbase[0][t] = base;
      wbase[1][t] = base + c0;
      wbase[2][t] = base + c0 + c1;
      wbase[3][t] = base + c0 + c1 + c2;
    }
    __syncthreads();
    idxbuf[e * B_TOTAL + wbase[wave][e] + rank] = b;
    return;
  }

  if (bid >= 384) {            // W3: (256,32) -> (16,256) with rows 8..15 = 0
    int e = bid - 384;
    int k = threadIdx.x;
#pragma unroll
    for (int o = 0; o < 16; ++o) {
      float v = (o < DA) ? W3[((size_t)e * H_DIM + k) * OUT_COLS + o] : 0.f;
      W3t[((size_t)e * 16 + o) * H_DIM + k] = (_Float16)v;
    }
    return;
  }

  // ---- weight transpose: 4 consecutive 32x32 tiles per block ----
  __shared__ float tile[32][33];
  int tx = threadIdx.x & 31, ty = threadIdx.x >> 5;  // 32x8
  for (int rep = 0; rep < 4; ++rep) {
    int tb = bid * 4 + rep;    // 0..1535
    const float* S; _Float16* D; int K, N, k0, n0;
    if (tb < 1024) {           // W1: (512,256) -> (256,512), 128 tiles/expert
      int e = tb >> 7, tt = tb & 127;
      K = F_DIM; N = H_DIM; k0 = (tt >> 3) * 32; n0 = (tt & 7) * 32;
      S = W1 + (size_t)e * F_DIM * H_DIM;
      D = W1t + (size_t)e * H_DIM * F_DIM;
    } else {                   // W2: (256,256) -> (256,256), 64 tiles/expert
      int r = tb - 1024;
      int e = r >> 6, tt = r & 63;
      K = H_DIM; N = H_DIM; k0 = (tt >> 3) * 32; n0 = (tt & 7) * 32;
      S = W2 + (size_t)e * H_DIM * H_DIM;
      D = W2t + (size_t)e * H_DIM * H_DIM;
    }
#pragma unroll
    for (int r = 0; r < 32; r += 8)
      tile[ty + r][tx] = S[(size_t)(k0 + ty + r) * N + (n0 + tx)];
    __syncthreads();
#pragma unroll
    for (int r = 0; r < 32; r += 8)
      D[(size_t)(n0 + ty + r) * K + (k0 + tx)] = (_Float16)tile[tx][ty + r];
    __syncthreads();           // WAR on tile before next rep
  }
}

// ---------------- fused gather + 3-layer expert MLP ----------------
// 520 blocks x 8 waves (512 thr). Wave owns 32 hidden rows (2 m-tiles x 2 s-tiles).
// LDS = 2 x [32][264] fp16: bufA = X cols 0..255 -> later H2; bufB = X cols 256..511
// -> later H1. X staged in one shot (8 float4/thread, single latency event) with the
// W1 depth-5 register pipeline issued while X is in flight. Depth-5 (~650cy of issue
// distance) covers L3 weight latency (weights are L3-resident: prior-iteration fill
// evicted L2; k_setup's writeback landed them in L3).
__global__ __launch_bounds__(512, 4) void k_mlp(
    const float* __restrict__ X,
    const _Float16* __restrict__ W1t,
    const _Float16* __restrict__ W2t,
    const _Float16* __restrict__ W3t,
    const float* __restrict__ b1,
    const float* __restrict__ b2,
    const float* __restrict__ b3,
    const int* __restrict__ counts,
    const int* __restrict__ idxbuf,
    float* __restrict__ out)
{
  __shared__ _Float16 bufA[TM][HSTRIDE];  // 16896 B
  __shared__ _Float16 bufB[TM][HSTRIDE];  // 16896 B

  int t = threadIdx.x;
  int lane = t & 63;
  int wave = t >> 6;          // 0..7
  int quad = lane >> 4;
  int l16 = lane & 15;
  int hbase = wave * 32;      // 32 hidden rows per wave
  int kq = quad * 8;
  int s = t >> 4, sub = t & 15;

  // --- map block -> (expert, tile0) over 32-rounded compact regions ---
  int slot0 = blockIdx.x * TM;
  int base = 0, e = 0, tile0 = -1, cnt = 0;
#pragma unroll
  for (int j = 0; j < E_NUM; ++j) {
    int c = counts[j];
    int rc = (c + 31) & ~31;
    if (tile0 < 0) {
      if (slot0 < base + rc) { e = j; tile0 = slot0 - base; cnt = c; }
      else base += rc;
    }
  }
  if (tile0 < 0) return;

  const float4v vzero = {0.f, 0.f, 0.f, 0.f};
  bool valid = (tile0 + s) < cnt;
  int xrow = valid ? idxbuf[e * B_TOTAL + tile0 + s] : 0;
  const float* src = X + (size_t)xrow * F_DIM;

  // --- X gather: all 8 float4 issued together (one latency event) ---
  float4v xr[8];
#pragma unroll
  for (int i = 0; i < 8; ++i)
    xr[i] = *(const float4v*)(src + sub * 4 + i * 64);

  // --- layer-1 weight prefetch (depth-5 modulo pipeline, 2 m-tiles) ---
  // issued while X loads are still in flight
  const _Float16* wb = W1t + ((size_t)e * H_DIM + hbase + l16) * F_DIM + kq;
  half8 a_p[5][2];
#pragma unroll
  for (int p = 0; p < 5; ++p)
#pragma unroll
    for (int mt = 0; mt < 2; ++mt)
      a_p[p][mt] = *(const half8*)(wb + (size_t)mt * 16 * F_DIM + p * 32);

  // --- land X: chunk0 -> bufA, chunk1 -> bufB ---
#pragma unroll
  for (int i = 0; i < 8; ++i) {
    int c = sub * 4 + i * 64;
    float4v v = valid ? xr[i] : vzero;
    half4 h;
    h[0] = (_Float16)v.x; h[1] = (_Float16)v.y;
    h[2] = (_Float16)v.z; h[3] = (_Float16)v.w;
    if (i < 4) *(half4*)&bufA[s][c] = h;
    else       *(half4*)&bufB[s][c - 256] = h;
  }
  __syncthreads();

  float4v acc[2][2];
#pragma unroll
  for (int mt = 0; mt < 2; ++mt)
#pragma unroll
    for (int st = 0; st < 2; ++st) acc[mt][st] = vzero;

  // ======== Layer 1: 16 uninterrupted K-iterations over bufA then bufB ========
#pragma unroll
  for (int kb = 0; kb < F_DIM; kb += 32) {
    int p = (kb >> 5) % 5;
    half8 a_cur[2];
#pragma unroll
    for (int mt = 0; mt < 2; ++mt) a_cur[mt] = a_p[p][mt];
    if (kb + 160 < F_DIM) {
#pragma unroll
      for (int mt = 0; mt < 2; ++mt)
        a_p[p][mt] = *(const half8*)(wb + (size_t)mt * 16 * F_DIM + kb + 160);
    }
    half8 b_cur[2];
    if (kb < 256) {
#pragma unroll
      for (int st = 0; st < 2; ++st)
        b_cur[st] = *(const half8*)&bufA[st * 16 + l16][kb + kq];
    } else {
#pragma unroll
      for (int st = 0; st < 2; ++st)
        b_cur[st] = *(const half8*)&bufB[st * 16 + l16][kb - 256 + kq];
    }
#pragma unroll
    for (int mt = 0; mt < 2; ++mt)
#pragma unroll
      for (int st = 0; st < 2; ++st)
        acc[mt][st] = __builtin_amdgcn_mfma_f32_16x16x32_f16(a_cur[mt], b_cur[st], acc[mt][st], 0, 0, 0);
  }

  // --- issue layer-2 weight prefetch (depth-5) before barrier ---
  const _Float16* wb2 = W2t + ((size_t)e * H_DIM + hbase + l16) * H_DIM + kq;
#pragma unroll
  for (int p = 0; p < 5; ++p)
#pragma unroll
    for (int mt = 0; mt < 2; ++mt)
      a_p[p][mt] = *(const half8*)(wb2 + (size_t)mt * 16 * H_DIM + p * 32);

  __syncthreads();  // all waves done reading bufB as X before H1 lands there

  // layer-1 epilogue: bias + relu -> bufB (= H1[sample][hidden])
#pragma unroll
  for (int mt = 0; mt < 2; ++mt) {
    int h0 = hbase + mt * 16 + quad * 4;
    float4v bb = *(const float4v*)&b1[e * H_DIM + h0];
#pragma unroll
    for (int st = 0; st < 2; ++st) {
      half4 hv;
#pragma unroll
      for (int r = 0; r < 4; ++r) {
        float v = acc[mt][st][r] + bb[r];
        hv[r] = (_Float16)(v > 0.f ? v : 0.f);
      }
      *(half4*)&bufB[st * 16 + l16][h0] = hv;
    }
  }
  __syncthreads();

  // ======== Layer 2: H2^T[h][s] = sum_k W2t[h][k] * H1[s][k] ========
#pragma unroll
  for (int mt = 0; mt < 2; ++mt)
#pragma unroll
    for (int st = 0; st < 2; ++st) acc[mt][st] = vzero;

#pragma unroll
  for (int kb = 0; kb < H_DIM; kb += 32) {
    int p = (kb >> 5) % 5;
    half8 a_cur[2];
#pragma unroll
    for (int mt = 0; mt < 2; ++mt) a_cur[mt] = a_p[p][mt];
    if (kb + 160 < H_DIM) {
#pragma unroll
      for (int mt = 0; mt < 2; ++mt)
        a_p[p][mt] = *(const half8*)(wb2 + (size_t)mt * 16 * H_DIM + kb + 160);
    }
    half8 b_cur[2];
#pragma unroll
    for (int st = 0; st < 2; ++st)
      b_cur[st] = *(const half8*)&bufB[st * 16 + l16][kb + kq];
#pragma unroll
    for (int mt = 0; mt < 2; ++mt)
#pragma unroll
      for (int st = 0; st < 2; ++st)
        acc[mt][st] = __builtin_amdgcn_mfma_f32_16x16x32_f16(a_cur[mt], b_cur[st], acc[mt][st], 0, 0, 0);
  }

  // layer-2 epilogue -> bufA (= H2; X chunk0 dead — all waves past barrier 2)
#pragma unroll
  for (int mt = 0; mt < 2; ++mt) {
    int h0 = hbase + mt * 16 + quad * 4;
    float4v bb = *(const float4v*)&b2[e * H_DIM + h0];
#pragma unroll
    for (int st = 0; st < 2; ++st) {
      half4 hv;
#pragma unroll
      for (int r = 0; r < 4; ++r) {
        float v = acc[mt][st][r] + bb[r];
        hv[r] = (_Float16)(v > 0.f ? v : 0.f);
      }
      *(half4*)&bufA[st * 16 + l16][h0] = hv;
    }
  }

  // --- waves 0,1: prefetch W3 before the barrier ---
  half8 af[8];
  const _Float16* wb3 = W3t + ((size_t)e * 16 + l16) * H_DIM + kq;
  if (wave < 2) {
#pragma unroll
    for (int i = 0; i < 8; ++i) af[i] = *(const half8*)(wb3 + i * 32);
  }
  __syncthreads();

  // ======== Layer 3: waves 0,1 each compute one 16-sample out tile ========
  if (wave < 2) {
    float4v acc3 = vzero;
#pragma unroll
    for (int i = 0; i < 8; ++i) {
      half8 bfrag = *(const half8*)&bufA[wave * 16 + l16][i * 32 + kq];
      acc3 = __builtin_amdgcn_mfma_f32_16x16x32_f16(af[i], bfrag, acc3, 0, 0, 0);
    }
    int si = tile0 + wave * 16 + l16;
    if (quad < 2 && si < cnt) {
      int row = idxbuf[e * B_TOTAL + si];
      float4v bb = *(const float4v*)&b3[e * OUT_COLS + quad * 4];
      float4v y;
#pragma unroll
      for (int r = 0; r < 4; ++r) y[r] = acc3[r] + bb[r];
      *(float4v*)&out[(size_t)row * DA + quad * 4] = y;
    }
  }
}

extern "C" void kernel_launch(void* const* d_in, const int* in_sizes, int n_in,
                              void* d_out, int out_size, void* d_ws, size_t ws_size,
                              hipStream_t stream) {
  const float* features = (const float*)d_in[0];
  const float* W1 = (const float*)d_in[1];
  const float* b1 = (const float*)d_in[2];
  const float* W2 = (const float*)d_in[3];
  const float* b2 = (const float*)d_in[4];
  const float* W3 = (const float*)d_in[5];
  const float* b3 = (const float*)d_in[6];
  const int* act = (const int*)d_in[7];
  float* out = (float*)d_out;

  char* ws = (char*)d_ws;
  int* counts = (int*)ws;                                      // 256 B
  int* idxbuf = (int*)(ws + 256);                              // 512 KiB
  _Float16* W1t = (_Float16*)(ws + 256 + 524288);              // 2 MiB
  _Float16* W2t = (_Float16*)(ws + 256 + 524288 + 2097152);    // 1 MiB
  _Float16* W3t = (_Float16*)(ws + 256 + 524288 + 2097152 + 1048576);  // 64 KiB

  hipMemsetAsync(counts, 0, 256, stream);
  k_setup<<<SETUP_BLOCKS, 256, 0, stream>>>(W1, W2, W3, W1t, W2t, W3t,
                                            act, counts, idxbuf);
  k_mlp<<<MLP_BLOCKS, 512, 0, stream>>>(features, W1t, W2t, W3t,
                                        b1, b2, b3, counts, idxbuf, out);
}

// Round 5
// 125.961 us; speedup vs baseline: 1.0574x; 1.0044x over previous
//
#include <hip/hip_runtime.h>

#define B_TOTAL 16384
#define F_DIM 512
#define H_DIM 256
#define E_NUM 8
#define OUT_COLS 32
#define DA 8
#define TM 64                 // samples per block
#define HSTRIDE (H_DIM + 8)   // 264 halves: rows 16B-aligned
#define C_CAP 36              // per-expert tile capacity; 8*36=288 >= max total tiles (263)
#define MLP_BLOCKS (E_NUM * C_CAP)  // 288
#define SETUP_BLOCKS 456      // 256 W1-transpose + 128 W2-transpose + 8 W3 + 64 bucket

typedef __attribute__((ext_vector_type(8))) _Float16 half8;
typedef __attribute__((ext_vector_type(4))) _Float16 half4;
typedef __attribute__((ext_vector_type(4))) float float4v;

// ---------------- merged setup: weight prep + bucket in one dispatch ----------------
// XCD-aligned: transpose/pack blocks for expert e have (bid&7)==e, so expert e's fp16
// weights are written through XCD e's L2 and stay resident for k_mlp (whose blocks for
// expert e also land on XCD e). blocks 0..255: W1 (4 tiles ea); 256..383: W2 (4 tiles
// ea); 384..391: W3 pack; 392..455: bucket.
__global__ void k_setup(const float* __restrict__ W1, const float* __restrict__ W2,
                        const float* __restrict__ W3,
                        _Float16* __restrict__ W1t, _Float16* __restrict__ W2t,
                        _Float16* __restrict__ W3t,
                        const int* __restrict__ act, int* __restrict__ counts,
                        int* __restrict__ idxbuf) {
  int bid = blockIdx.x;
  if (bid >= 392) {
    // ---- bucket samples by expert (block-aggregated atomics) ----
    __shared__ int wcnt[4][E_NUM];
    __shared__ int wbase[4][E_NUM];
    int t = threadIdx.x;
    int lane = t & 63, wave = t >> 6;
    int b = (bid - 392) * 256 + t;
    int e = act[b] & 7;

    unsigned long long mymask = 0;
#pragma unroll
    for (int v = 0; v < E_NUM; ++v) {
      unsigned long long m = __ballot(e == v);
      if (lane == 0) wcnt[wave][v] = (int)__popcll(m);
      if (e == v) mymask = m;
    }
    int rank = (int)__popcll(mymask & ((1ull << lane) - 1ull));
    __syncthreads();
    if (t < E_NUM) {
      int c0 = wcnt[0][t], c1 = wcnt[1][t], c2 = wcnt[2][t], c3 = wcnt[3][t];
      int base = atomicAdd(&counts[t], c0 + c1 + c2 + c3);
      wbase[0][t] = base;
      wbase[1][t] = base + c0;
      wbase[2][t] = base + c0 + c1;
      wbase[3][t] = base + c0 + c1 + c2;
    }
    __syncthreads();
    idxbuf[e * B_TOTAL + wbase[wave][e] + rank] = b;
    return;
  }

  if (bid >= 384) {            // W3: (256,32) -> (16,256) with rows 8..15 = 0
    int e = bid - 384;         // == bid&7: XCD-aligned
    int k = threadIdx.x;
#pragma unroll
    for (int o = 0; o < 16; ++o) {
      float v = (o < DA) ? W3[((size_t)e * H_DIM + k) * OUT_COLS + o] : 0.f;
      W3t[((size_t)e * 16 + o) * H_DIM + k] = (_Float16)v;
    }
    return;
  }

  // ---- weight transpose: expert = bid&7 (XCD-aligned), 4 consecutive 32x32 tiles ----
  __shared__ float tile[32][33];
  int tx = threadIdx.x & 31, ty = threadIdx.x >> 5;  // 32x8
  int e = bid & 7;
  const float* S; _Float16* D; int K, N, tt0;
  if (bid < 256) {             // W1: (512,256) -> (256,512); 128 tiles/e; 32 blocks/e
    K = F_DIM; N = H_DIM; tt0 = (bid >> 3) * 4;
    S = W1 + (size_t)e * F_DIM * H_DIM;
    D = W1t + (size_t)e * H_DIM * F_DIM;
  } else {                     // W2: (256,256) -> (256,256); 64 tiles/e; 16 blocks/e
    K = H_DIM; N = H_DIM; tt0 = ((bid - 256) >> 3) * 4;
    S = W2 + (size_t)e * H_DIM * H_DIM;
    D = W2t + (size_t)e * H_DIM * H_DIM;
  }
  for (int rep = 0; rep < 4; ++rep) {
    int tt = tt0 + rep;
    int k0 = (tt >> 3) * 32, n0 = (tt & 7) * 32;
#pragma unroll
    for (int r = 0; r < 32; r += 8)
      tile[ty + r][tx] = __builtin_nontemporal_load(&S[(size_t)(k0 + ty + r) * N + (n0 + tx)]);
    __syncthreads();
#pragma unroll
    for (int r = 0; r < 32; r += 8)
      D[(size_t)(n0 + ty + r) * K + (k0 + tx)] = (_Float16)tile[tx][ty + r];
    __syncthreads();           // WAR on tile before next rep
  }
}

// ---------------- fused gather + 3-layer expert MLP (XCD-pinned, TM=64) -------------
// 288 blocks x 16 waves (1024 thr). Block bid -> expert (bid&7), tile (bid>>3):
// round-robin dispatch lands expert e's blocks on XCD e, whose L2 holds e's weights
// (written there by k_setup). Wave owns 16 hidden rows x 64 samples (4 s-tiles).
// TM=64 halves per-sample weight re-read traffic vs TM=32. X loads / out stores are
// non-temporal so streaming X doesn't evict pinned weights. Orphan remap covers
// expert skew (provably: 8*C_CAP=288 >= total tiles <= 263).
__global__ __launch_bounds__(1024, 4) void k_mlp(
    const float* __restrict__ X,
    const _Float16* __restrict__ W1t,
    const _Float16* __restrict__ W2t,
    const _Float16* __restrict__ W3t,
    const float* __restrict__ b1,
    const float* __restrict__ b2,
    const float* __restrict__ b3,
    const int* __restrict__ counts,
    const int* __restrict__ idxbuf,
    float* __restrict__ out)
{
  __shared__ _Float16 bufA[TM][HSTRIDE];  // X cols 0..255 -> later H2 (33792 B)
  __shared__ _Float16 bufB[TM][HSTRIDE];  // X cols 256..511 -> later H1

  int t = threadIdx.x;
  int lane = t & 63;
  int wave = t >> 6;          // 0..15
  int quad = lane >> 4;
  int l16 = lane & 15;
  int hbase = wave * 16;      // 16 hidden rows per wave
  int kq = quad * 8;
  int s = t >> 4, sub = t & 15;   // staging: 16 threads per sample row

  int x = blockIdx.x & 7;
  int li = blockIdx.x >> 3;   // 0..35

  // --- speculative idxbuf load (primary mapping), issued at cycle 0 ---
  int raw = idxbuf[x * B_TOTAL + li * TM + s];

  // --- counts (uniform) + primary/orphan mapping ---
  int cnt_x = counts[x];
  int tt_x = (cnt_x + TM - 1) >> 6;
  int e = x, tile = li, cnt = cnt_x;
  if (li >= tt_x) {
    // orphan remap (handles skewed expert distributions; uniform per block)
    int ttj[E_NUM];
#pragma unroll
    for (int j = 0; j < E_NUM; ++j) ttj[j] = (counts[j] + TM - 1) >> 6;
    int rank = 0;
#pragma unroll
    for (int j = 0; j < E_NUM; ++j) { int d = li - ttj[j]; rank += d > 0 ? d : 0; }
#pragma unroll
    for (int j = 0; j < E_NUM; ++j) if (j < x && li >= ttj[j]) ++rank;
    int fe = -1, ft = 0, accum = 0;
#pragma unroll
    for (int j = 0; j < E_NUM; ++j) {
      int lo = ttj[j] - C_CAP; lo = lo > 0 ? lo : 0;
      if (fe < 0 && rank < accum + lo) { fe = j; ft = C_CAP + (rank - accum); }
      accum += lo;
    }
    if (fe < 0) return;
    e = fe; tile = ft; cnt = counts[e];
    raw = idxbuf[e * B_TOTAL + tile * TM + s];
  }
  int tile0 = tile * TM;

  const float4v vzero = {0.f, 0.f, 0.f, 0.f};
  bool valid = (tile0 + s) < cnt;
  int xrow = raw & (B_TOTAL - 1);   // clamp: speculative entries may be garbage
  const float* src = X + (size_t)xrow * F_DIM + sub * 4;

  // --- X gather: all 8 float4 issued together, non-temporal (no L2 pollution) ---
  float4v xr[8];
#pragma unroll
  for (int i = 0; i < 8; ++i)
    xr[i] = __builtin_nontemporal_load((const float4v*)(src + i * 64));

  // --- layer-1 weight prefetch (depth-5 modulo pipeline), issued while X in flight ---
  const _Float16* wb = W1t + ((size_t)e * H_DIM + hbase + l16) * F_DIM + kq;
  half8 a_p[5];
#pragma unroll
  for (int p = 0; p < 5; ++p)
    a_p[p] = *(const half8*)(wb + p * 32);

  // --- land X: chunk0 -> bufA, chunk1 -> bufB ---
#pragma unroll
  for (int i = 0; i < 8; ++i) {
    int c = sub * 4 + i * 64;
    float4v v = valid ? xr[i] : vzero;
    half4 h;
    h[0] = (_Float16)v.x; h[1] = (_Float16)v.y;
    h[2] = (_Float16)v.z; h[3] = (_Float16)v.w;
    if (i < 4) *(half4*)&bufA[s][c] = h;
    else       *(half4*)&bufB[s][c - 256] = h;
  }
  __syncthreads();

  float4v acc[4];
#pragma unroll
  for (int st = 0; st < 4; ++st) acc[st] = vzero;

  // ======== Layer 1: 16 K-iterations over bufA then bufB ========
#pragma unroll
  for (int kb = 0; kb < F_DIM; kb += 32) {
    int p = (kb >> 5) % 5;
    half8 a_cur = a_p[p];
    if (kb + 160 < F_DIM)
      a_p[p] = *(const half8*)(wb + kb + 160);
    half8 b_cur[4];
    if (kb < 256) {
#pragma unroll
      for (int st = 0; st < 4; ++st)
        b_cur[st] = *(const half8*)&bufA[st * 16 + l16][kb + kq];
    } else {
#pragma unroll
      for (int st = 0; st < 4; ++st)
        b_cur[st] = *(const half8*)&bufB[st * 16 + l16][kb - 256 + kq];
    }
#pragma unroll
    for (int st = 0; st < 4; ++st)
      acc[st] = __builtin_amdgcn_mfma_f32_16x16x32_f16(a_cur, b_cur[st], acc[st], 0, 0, 0);
  }

  // --- issue layer-2 weight prefetch (depth-5) before barrier ---
  const _Float16* wb2 = W2t + ((size_t)e * H_DIM + hbase + l16) * H_DIM + kq;
#pragma unroll
  for (int p = 0; p < 5; ++p)
    a_p[p] = *(const half8*)(wb2 + p * 32);

  __syncthreads();  // all waves done reading bufB as X before H1 lands there

  // layer-1 epilogue: bias + relu -> bufB (= H1[sample][hidden])
  {
    int h0 = hbase + quad * 4;
    float4v bb = *(const float4v*)&b1[e * H_DIM + h0];
#pragma unroll
    for (int st = 0; st < 4; ++st) {
      half4 hv;
#pragma unroll
      for (int r = 0; r < 4; ++r) {
        float v = acc[st][r] + bb[r];
        hv[r] = (_Float16)(v > 0.f ? v : 0.f);
      }
      *(half4*)&bufB[st * 16 + l16][h0] = hv;
    }
  }
  __syncthreads();

  // ======== Layer 2: H2^T[h][s] = sum_k W2t[h][k] * H1[s][k] ========
#pragma unroll
  for (int st = 0; st < 4; ++st) acc[st] = vzero;

#pragma unroll
  for (int kb = 0; kb < H_DIM; kb += 32) {
    int p = (kb >> 5) % 5;
    half8 a_cur = a_p[p];
    if (kb + 160 < H_DIM)
      a_p[p] = *(const half8*)(wb2 + kb + 160);
    half8 b_cur[4];
#pragma unroll
    for (int st = 0; st < 4; ++st)
      b_cur[st] = *(const half8*)&bufB[st * 16 + l16][kb + kq];
#pragma unroll
    for (int st = 0; st < 4; ++st)
      acc[st] = __builtin_amdgcn_mfma_f32_16x16x32_f16(a_cur, b_cur[st], acc[st], 0, 0, 0);
  }

  // layer-2 epilogue -> bufA (= H2; X chunk0 dead — all waves past barrier 2)
  {
    int h0 = hbase + quad * 4;
    float4v bb = *(const float4v*)&b2[e * H_DIM + h0];
#pragma unroll
    for (int st = 0; st < 4; ++st) {
      half4 hv;
#pragma unroll
      for (int r = 0; r < 4; ++r) {
        float v = acc[st][r] + bb[r];
        hv[r] = (_Float16)(v > 0.f ? v : 0.f);
      }
      *(half4*)&bufA[st * 16 + l16][h0] = hv;
    }
  }

  // --- waves 0..3: prefetch W3 before the barrier ---
  half8 af[8];
  const _Float16* wb3 = W3t + ((size_t)e * 16 + l16) * H_DIM + kq;
  if (wave < 4) {
#pragma unroll
    for (int i = 0; i < 8; ++i) af[i] = *(const half8*)(wb3 + i * 32);
  }
  __syncthreads();

  // ======== Layer 3: waves 0..3 each compute one 16-sample out tile ========
  if (wave < 4) {
    float4v acc3 = vzero;
#pragma unroll
    for (int i = 0; i < 8; ++i) {
      half8 bfrag = *(const half8*)&bufA[wave * 16 + l16][i * 32 + kq];
      acc3 = __builtin_amdgcn_mfma_f32_16x16x32_f16(af[i], bfrag, acc3, 0, 0, 0);
    }
    int si = tile0 + wave * 16 + l16;
    if (quad < 2 && si < cnt) {
      int row = idxbuf[e * B_TOTAL + si];
      float4v bb = *(const float4v*)&b3[e * OUT_COLS + quad * 4];
      float4v y;
#pragma unroll
      for (int r = 0; r < 4; ++r) y[r] = acc3[r] + bb[r];
      __builtin_nontemporal_store(y, (float4v*)&out[(size_t)row * DA + quad * 4]);
    }
  }
}

extern "C" void kernel_launch(void* const* d_in, const int* in_sizes, int n_in,
                              void* d_out, int out_size, void* d_ws, size_t ws_size,
                              hipStream_t stream) {
  const float* features = (const float*)d_in[0];
  const float* W1 = (const float*)d_in[1];
  const float* b1 = (const float*)d_in[2];
  const float* W2 = (const float*)d_in[3];
  const float* b2 = (const float*)d_in[4];
  const float* W3 = (const float*)d_in[5];
  const float* b3 = (const float*)d_in[6];
  const int* act = (const int*)d_in[7];
  float* out = (float*)d_out;

  char* ws = (char*)d_ws;
  int* counts = (int*)ws;                                      // 256 B
  int* idxbuf = (int*)(ws + 256);                              // 512 KiB
  _Float16* W1t = (_Float16*)(ws + 256 + 524288);              // 2 MiB
  _Float16* W2t = (_Float16*)(ws + 256 + 524288 + 2097152);    // 1 MiB
  _Float16* W3t = (_Float16*)(ws + 256 + 524288 + 2097152 + 1048576);  // 64 KiB

  hipMemsetAsync(counts, 0, 256, stream);
  k_setup<<<SETUP_BLOCKS, 256, 0, stream>>>(W1, W2, W3, W1t, W2t, W3t,
                                            act, counts, idxbuf);
  k_mlp<<<MLP_BLOCKS, 1024, 0, stream>>>(features, W1t, W2t, W3t,
                                         b1, b2, b3, counts, idxbuf, out);
}

// Round 6
// 125.538 us; speedup vs baseline: 1.0610x; 1.0034x over previous
//
#include <hip/hip_runtime.h>

#define B_TOTAL 16384
#define F_DIM 512
#define H_DIM 256
#define E_NUM 8
#define OUT_COLS 32
#define DA 8
#define TM 64                 // samples per block
#define HSTRIDE (H_DIM + 8)   // 264 halves: rows 16B-aligned
#define C_CAP 36              // per-expert tile capacity; 8*36=288 >= max total tiles (263)
#define MLP_BLOCKS (E_NUM * C_CAP)  // 288
#define SETUP_BLOCKS 456      // 256 W1-transpose + 128 W2-transpose + 8 W3 + 64 bucket

typedef __attribute__((ext_vector_type(8))) _Float16 half8;
typedef __attribute__((ext_vector_type(4))) _Float16 half4;
typedef __attribute__((ext_vector_type(4))) float float4v;

// ---------------- merged setup: weight prep + bucket in one dispatch ----------------
// XCD-aligned: transpose/pack blocks for expert e have (bid&7)==e, so expert e's fp16
// weights are written through XCD e's L2 and stay resident for k_mlp (whose blocks for
// expert e also land on XCD e).
// blocks 0..255: W1 64x64-tile transpose (32 tiles/e); 256..383: W2 (16 tiles/e);
// 384..391: W3 pack; 392..455: bucket.
// Transpose critical path: ONE global-read latency event (4x float4/thread, coalesced)
// + 1 barrier + vectorized half8 writes — vs 4 reps x 8 barriers of scalar I/O before.
__global__ void k_setup(const float* __restrict__ W1, const float* __restrict__ W2,
                        const float* __restrict__ W3,
                        _Float16* __restrict__ W1t, _Float16* __restrict__ W2t,
                        _Float16* __restrict__ W3t,
                        const int* __restrict__ act, int* __restrict__ counts,
                        int* __restrict__ idxbuf) {
  int bid = blockIdx.x;
  if (bid >= 392) {
    // ---- bucket samples by expert (block-aggregated atomics) ----
    __shared__ int wcnt[4][E_NUM];
    __shared__ int wbase[4][E_NUM];
    int t = threadIdx.x;
    int lane = t & 63, wave = t >> 6;
    int b = (bid - 392) * 256 + t;
    int e = act[b] & 7;

    unsigned long long mymask = 0;
#pragma unroll
    for (int v = 0; v < E_NUM; ++v) {
      unsigned long long m = __ballot(e == v);
      if (lane == 0) wcnt[wave][v] = (int)__popcll(m);
      if (e == v) mymask = m;
    }
    int rank = (int)__popcll(mymask & ((1ull << lane) - 1ull));
    __syncthreads();
    if (t < E_NUM) {
      int c0 = wcnt[0][t], c1 = wcnt[1][t], c2 = wcnt[2][t], c3 = wcnt[3][t];
      int base = atomicAdd(&counts[t], c0 + c1 + c2 + c3);
      wbase[0][t] = base;
      wbase[1][t] = base + c0;
      wbase[2][t] = base + c0 + c1;
      wbase[3][t] = base + c0 + c1 + c2;
    }
    __syncthreads();
    idxbuf[e * B_TOTAL + wbase[wave][e] + rank] = b;
    return;
  }

  if (bid >= 384) {            // W3: (256,32) -> (16,256) with rows 8..15 = 0
    int e = bid - 384;         // == bid&7: XCD-aligned
    int k = threadIdx.x;
#pragma unroll
    for (int o = 0; o < 16; ++o) {
      float v = (o < DA) ? W3[((size_t)e * H_DIM + k) * OUT_COLS + o] : 0.f;
      W3t[((size_t)e * 16 + o) * H_DIM + k] = (_Float16)v;
    }
    return;
  }

  // ---- weight transpose: one 64x64 tile per block, expert = bid&7 ----
  __shared__ _Float16 hs[64][72];   // hs[h][k], +8 pad
  int t = threadIdx.x;
  int r = t >> 2, j = t & 3;        // r: source row (k), 4 threads per row
  int e = bid & 7;
  const float* S; _Float16* D; int K, tile;
  if (bid < 256) {                  // W1: (512,256) -> (256,512); 8 k-tiles x 4 h-tiles
    tile = bid >> 3; K = F_DIM;
    S = W1 + (size_t)e * F_DIM * H_DIM;
    D = W1t + (size_t)e * H_DIM * F_DIM;
  } else {                          // W2: (256,256) -> (256,256); 4 k-tiles x 4 h-tiles
    tile = (bid - 256) >> 3; K = H_DIM;
    S = W2 + (size_t)e * H_DIM * H_DIM;
    D = W2t + (size_t)e * H_DIM * H_DIM;
  }
  int k0 = (tile >> 2) * 64, h0 = (tile & 3) * 64;

  const float* srow = S + (size_t)(k0 + r) * H_DIM + h0;
  float4v v[4];
#pragma unroll
  for (int i = 0; i < 4; ++i)       // all 4 reads issued together: one latency event
    v[i] = *(const float4v*)(srow + (j + 4 * i) * 4);
#pragma unroll
  for (int i = 0; i < 4; ++i) {
    int c = (j + 4 * i) * 4;        // source col = h index
    hs[c + 0][r] = (_Float16)v[i].x;
    hs[c + 1][r] = (_Float16)v[i].y;
    hs[c + 2][r] = (_Float16)v[i].z;
    hs[c + 3][r] = (_Float16)v[i].w;
  }
  __syncthreads();
  _Float16* drow = D + (size_t)(h0 + r) * K + k0;   // r now: dest row (h)
#pragma unroll
  for (int i = 0; i < 2; ++i)
    *(half8*)(drow + (j + 4 * i) * 8) = *(const half8*)&hs[r][(j + 4 * i) * 8];
}

// ---------------- fused gather + 3-layer expert MLP (XCD-pinned, TM=64) -------------
// 288 blocks x 16 waves (1024 thr). Block bid -> expert (bid&7), tile (bid>>3):
// round-robin dispatch lands expert e's blocks on XCD e, whose L2 holds e's weights
// (written there by k_setup). Wave owns 16 hidden rows x 64 samples (4 s-tiles).
// X loads / out stores are non-temporal so streaming X doesn't evict pinned weights.
// Orphan remap covers expert skew (provably: 8*C_CAP=288 >= total tiles <= 263).
__global__ __launch_bounds__(1024, 4) void k_mlp(
    const float* __restrict__ X,
    const _Float16* __restrict__ W1t,
    const _Float16* __restrict__ W2t,
    const _Float16* __restrict__ W3t,
    const float* __restrict__ b1,
    const float* __restrict__ b2,
    const float* __restrict__ b3,
    const int* __restrict__ counts,
    const int* __restrict__ idxbuf,
    float* __restrict__ out)
{
  __shared__ _Float16 bufA[TM][HSTRIDE];  // X cols 0..255 -> later H2 (33792 B)
  __shared__ _Float16 bufB[TM][HSTRIDE];  // X cols 256..511 -> later H1

  int t = threadIdx.x;
  int lane = t & 63;
  int wave = t >> 6;          // 0..15
  int quad = lane >> 4;
  int l16 = lane & 15;
  int hbase = wave * 16;      // 16 hidden rows per wave
  int kq = quad * 8;
  int s = t >> 4, sub = t & 15;   // staging: 16 threads per sample row

  int x = blockIdx.x & 7;
  int li = blockIdx.x >> 3;   // 0..35

  // --- speculative idxbuf load (primary mapping), issued at cycle 0 ---
  int raw = idxbuf[x * B_TOTAL + li * TM + s];

  // --- counts (uniform) + primary/orphan mapping ---
  int cnt_x = counts[x];
  int tt_x = (cnt_x + TM - 1) >> 6;
  int e = x, tile = li, cnt = cnt_x;
  if (li >= tt_x) {
    // orphan remap (handles skewed expert distributions; uniform per block)
    int ttj[E_NUM];
#pragma unroll
    for (int j = 0; j < E_NUM; ++j) ttj[j] = (counts[j] + TM - 1) >> 6;
    int rank = 0;
#pragma unroll
    for (int j = 0; j < E_NUM; ++j) { int d = li - ttj[j]; rank += d > 0 ? d : 0; }
#pragma unroll
    for (int j = 0; j < E_NUM; ++j) if (j < x && li >= ttj[j]) ++rank;
    int fe = -1, ft = 0, accum = 0;
#pragma unroll
    for (int j = 0; j < E_NUM; ++j) {
      int lo = ttj[j] - C_CAP; lo = lo > 0 ? lo : 0;
      if (fe < 0 && rank < accum + lo) { fe = j; ft = C_CAP + (rank - accum); }
      accum += lo;
    }
    if (fe < 0) return;
    e = fe; tile = ft; cnt = counts[e];
    raw = idxbuf[e * B_TOTAL + tile * TM + s];
  }
  int tile0 = tile * TM;

  const float4v vzero = {0.f, 0.f, 0.f, 0.f};
  bool valid = (tile0 + s) < cnt;
  int xrow = raw & (B_TOTAL - 1);   // clamp: speculative entries may be garbage
  const float* src = X + (size_t)xrow * F_DIM + sub * 4;

  // --- X gather: all 8 float4 issued together, non-temporal (no L2 pollution) ---
  float4v xr[8];
#pragma unroll
  for (int i = 0; i < 8; ++i)
    xr[i] = __builtin_nontemporal_load((const float4v*)(src + i * 64));

  // --- layer-1 weight prefetch (depth-5 modulo pipeline), issued while X in flight ---
  const _Float16* wb = W1t + ((size_t)e * H_DIM + hbase + l16) * F_DIM + kq;
  half8 a_p[5];
#pragma unroll
  for (int p = 0; p < 5; ++p)
    a_p[p] = *(const half8*)(wb + p * 32);

  // --- land X: chunk0 -> bufA, chunk1 -> bufB ---
#pragma unroll
  for (int i = 0; i < 8; ++i) {
    int c = sub * 4 + i * 64;
    float4v v = valid ? xr[i] : vzero;
    half4 h;
    h[0] = (_Float16)v.x; h[1] = (_Float16)v.y;
    h[2] = (_Float16)v.z; h[3] = (_Float16)v.w;
    if (i < 4) *(half4*)&bufA[s][c] = h;
    else       *(half4*)&bufB[s][c - 256] = h;
  }
  __syncthreads();

  float4v acc[4];
#pragma unroll
  for (int st = 0; st < 4; ++st) acc[st] = vzero;

  // ======== Layer 1: 16 K-iterations over bufA then bufB ========
#pragma unroll
  for (int kb = 0; kb < F_DIM; kb += 32) {
    int p = (kb >> 5) % 5;
    half8 a_cur = a_p[p];
    if (kb + 160 < F_DIM)
      a_p[p] = *(const half8*)(wb + kb + 160);
    half8 b_cur[4];
    if (kb < 256) {
#pragma unroll
      for (int st = 0; st < 4; ++st)
        b_cur[st] = *(const half8*)&bufA[st * 16 + l16][kb + kq];
    } else {
#pragma unroll
      for (int st = 0; st < 4; ++st)
        b_cur[st] = *(const half8*)&bufB[st * 16 + l16][kb - 256 + kq];
    }
#pragma unroll
    for (int st = 0; st < 4; ++st)
      acc[st] = __builtin_amdgcn_mfma_f32_16x16x32_f16(a_cur, b_cur[st], acc[st], 0, 0, 0);
  }

  // --- issue layer-2 weight prefetch (depth-5) before barrier ---
  const _Float16* wb2 = W2t + ((size_t)e * H_DIM + hbase + l16) * H_DIM + kq;
#pragma unroll
  for (int p = 0; p < 5; ++p)
    a_p[p] = *(const half8*)(wb2 + p * 32);

  __syncthreads();  // all waves done reading bufB as X before H1 lands there

  // layer-1 epilogue: bias + relu -> bufB (= H1[sample][hidden])
  {
    int h0 = hbase + quad * 4;
    float4v bb = *(const float4v*)&b1[e * H_DIM + h0];
#pragma unroll
    for (int st = 0; st < 4; ++st) {
      half4 hv;
#pragma unroll
      for (int r = 0; r < 4; ++r) {
        float v = acc[st][r] + bb[r];
        hv[r] = (_Float16)(v > 0.f ? v : 0.f);
      }
      *(half4*)&bufB[st * 16 + l16][h0] = hv;
    }
  }
  __syncthreads();

  // ======== Layer 2: H2^T[h][s] = sum_k W2t[h][k] * H1[s][k] ========
#pragma unroll
  for (int st = 0; st < 4; ++st) acc[st] = vzero;

#pragma unroll
  for (int kb = 0; kb < H_DIM; kb += 32) {
    int p = (kb >> 5) % 5;
    half8 a_cur = a_p[p];
    if (kb + 160 < H_DIM)
      a_p[p] = *(const half8*)(wb2 + kb + 160);
    half8 b_cur[4];
#pragma unroll
    for (int st = 0; st < 4; ++st)
      b_cur[st] = *(const half8*)&bufB[st * 16 + l16][kb + kq];
#pragma unroll
    for (int st = 0; st < 4; ++st)
      acc[st] = __builtin_amdgcn_mfma_f32_16x16x32_f16(a_cur, b_cur[st], acc[st], 0, 0, 0);
  }

  // layer-2 epilogue -> bufA (= H2; X chunk0 dead — all waves past barrier 2)
  {
    int h0 = hbase + quad * 4;
    float4v bb = *(const float4v*)&b2[e * H_DIM + h0];
#pragma unroll
    for (int st = 0; st < 4; ++st) {
      half4 hv;
#pragma unroll
      for (int r = 0; r < 4; ++r) {
        float v = acc[st][r] + bb[r];
        hv[r] = (_Float16)(v > 0.f ? v : 0.f);
      }
      *(half4*)&bufA[st * 16 + l16][h0] = hv;
    }
  }

  // --- waves 0..3: prefetch W3 before the barrier ---
  half8 af[8];
  const _Float16* wb3 = W3t + ((size_t)e * 16 + l16) * H_DIM + kq;
  if (wave < 4) {
#pragma unroll
    for (int i = 0; i < 8; ++i) af[i] = *(const half8*)(wb3 + i * 32);
  }
  __syncthreads();

  // ======== Layer 3: waves 0..3 each compute one 16-sample out tile ========
  if (wave < 4) {
    float4v acc3 = vzero;
#pragma unroll
    for (int i = 0; i < 8; ++i) {
      half8 bfrag = *(const half8*)&bufA[wave * 16 + l16][i * 32 + kq];
      acc3 = __builtin_amdgcn_mfma_f32_16x16x32_f16(af[i], bfrag, acc3, 0, 0, 0);
    }
    int si = tile0 + wave * 16 + l16;
    if (quad < 2 && si < cnt) {
      int row = idxbuf[e * B_TOTAL + si];
      float4v bb = *(const float4v*)&b3[e * OUT_COLS + quad * 4];
      float4v y;
#pragma unroll
      for (int r = 0; r < 4; ++r) y[r] = acc3[r] + bb[r];
      __builtin_nontemporal_store(y, (float4v*)&out[(size_t)row * DA + quad * 4]);
    }
  }
}

extern "C" void kernel_launch(void* const* d_in, const int* in_sizes, int n_in,
                              void* d_out, int out_size, void* d_ws, size_t ws_size,
                              hipStream_t stream) {
  const float* features = (const float*)d_in[0];
  const float* W1 = (const float*)d_in[1];
  const float* b1 = (const float*)d_in[2];
  const float* W2 = (const float*)d_in[3];
  const float* b2 = (const float*)d_in[4];
  const float* W3 = (const float*)d_in[5];
  const float* b3 = (const float*)d_in[6];
  const int* act = (const int*)d_in[7];
  float* out = (float*)d_out;

  char* ws = (char*)d_ws;
  int* counts = (int*)ws;                                      // 256 B
  int* idxbuf = (int*)(ws + 256);                              // 512 KiB
  _Float16* W1t = (_Float16*)(ws + 256 + 524288);              // 2 MiB
  _Float16* W2t = (_Float16*)(ws + 256 + 524288 + 2097152);    // 1 MiB
  _Float16* W3t = (_Float16*)(ws + 256 + 524288 + 2097152 + 1048576);  // 64 KiB

  hipMemsetAsync(counts, 0, 256, stream);
  k_setup<<<SETUP_BLOCKS, 256, 0, stream>>>(W1, W2, W3, W1t, W2t, W3t,
                                            act, counts, idxbuf);
  k_mlp<<<MLP_BLOCKS, 1024, 0, stream>>>(features, W1t, W2t, W3t,
                                         b1, b2, b3, counts, idxbuf, out);
}